// Round 1
// baseline (164.413 us; speedup 1.0000x reference)
//
#include <hip/hip_runtime.h>
#include <math.h>

#define C_NUM 80
#define B_NUM 16
#define T_NUM 256
#define EPSF  1e-7f

__device__ __forceinline__ float softplusf(float z) {
    // logaddexp(0, z) = max(z,0) + log1p(exp(-|z|)), numerically stable
    return fmaxf(z, 0.0f) + log1pf(expf(-fabsf(z)));
}

__global__ __launch_bounds__(64)
void yolo_init(float* __restrict__ acc) {
    if (threadIdx.x < 12) acc[threadIdx.x] = 0.0f;
}

// One block = 256 consecutive anchors of one (scale, batch image).
// bid < 400           : scale 0 (H=80, A=6400, 25 chunks x 16 images)
// 400 <= bid < 512    : scale 1 (H=40, A=1600,  7 chunks x 16 images)
// 512 <= bid < 544    : scale 2 (H=20, A=400,   2 chunks x 16 images)
__global__ __launch_bounds__(256)
void yolo_main(const float* __restrict__ cls0, const float* __restrict__ reg0,
               const float* __restrict__ cls1, const float* __restrict__ reg1,
               const float* __restrict__ cls2, const float* __restrict__ reg2,
               const float* __restrict__ tboxes, const int* __restrict__ t_batch,
               const int* __restrict__ t_cls, float* __restrict__ acc)
{
    __shared__ float s_x1[T_NUM], s_y1[T_NUM], s_x2[T_NUM], s_y2[T_NUM], s_ar[T_NUM];
    __shared__ int   s_tc[T_NUM];
    __shared__ int   s_list[T_NUM];   // indices of targets belonging to image b, ascending
    __shared__ int   s_wcnt[4];
    __shared__ float s_red[4][4];

    const int tid = threadIdx.x;
    const int bid = blockIdx.x;

    int s, b, chunk, H; float stride;
    const float *clsp, *regp;
    if (bid < 400)      { s = 0; b = bid / 25;            chunk = bid % 25; clsp = cls0; regp = reg0; H = 80; stride =  8.f; }
    else if (bid < 512) { int r = bid - 400; s = 1; b = r / 7; chunk = r % 7; clsp = cls1; regp = reg1; H = 40; stride = 16.f; }
    else                { int r = bid - 512; s = 2; b = r / 2; chunk = r % 2; clsp = cls2; regp = reg2; H = 20; stride = 32.f; }
    const int A = H * H;

    // ---- stage all targets into LDS (tboxes rows are float4-aligned) ----
    {
        float4 t4 = reinterpret_cast<const float4*>(tboxes)[tid];
        s_x1[tid] = t4.x; s_y1[tid] = t4.y; s_x2[tid] = t4.z; s_y2[tid] = t4.w;
        s_ar[tid] = (t4.z - t4.x) * (t4.w - t4.y);
        s_tc[tid] = t_cls[tid];
    }
    // ---- order-preserving compaction of targets with t_batch == b ----
    const int lane = tid & 63, wave = tid >> 6;
    int match = (t_batch[tid] == b) ? 1 : 0;
    unsigned long long mask = __ballot(match != 0);
    if (lane == 0) s_wcnt[wave] = __popcll(mask);
    __syncthreads();
    int base = 0;
    #pragma unroll
    for (int w = 0; w < 4; ++w) if (w < wave) base += s_wcnt[w];
    const int nT = s_wcnt[0] + s_wcnt[1] + s_wcnt[2] + s_wcnt[3];
    if (match) {
        int pfx = __popcll(mask & (((unsigned long long)1 << lane) - 1ull));
        s_list[base + pfx] = tid;
    }
    __syncthreads();

    // ---- per-anchor computation ----
    const int a = chunk * 256 + tid;
    float cnt = 0.f, boxs = 0.f, clss = 0.f, objs = 0.f;
    if (a < A) {
        // decode predicted box
        const float* rp = regp + (b * 4) * A + a;
        float rx = rp[0], ry = rp[A], rw = rp[2 * A], rh = rp[3 * A];
        float gx = (float)(a % H), gy = (float)(a / H);
        float x = (1.f / (1.f + expf(-rx)) + gx) * stride;
        float y = (1.f / (1.f + expf(-ry)) + gy) * stride;
        float w = expf(rw) * stride;
        float h = expf(rh) * stride;
        float px1 = x - 0.5f * w, py1 = y - 0.5f * h;
        float px2 = x + 0.5f * w, py2 = y + 0.5f * h;
        float pw = px2 - px1, ph = py2 - py1;
        float parea = pw * ph;

        // best IoU over this image's targets (ascending t => argmax tie = first max)
        float maxiou = -1.f; int best = 0;
        for (int j = 0; j < nT; ++j) {
            int t = s_list[j];
            float ix = fminf(px2, s_x2[t]) - fmaxf(px1, s_x1[t]);
            float iy = fminf(py2, s_y2[t]) - fmaxf(py1, s_y1[t]);
            float inter = fmaxf(ix, 0.f) * fmaxf(iy, 0.f);
            float iou = inter / (parea + s_ar[t] - inter + EPSF);
            if (iou > maxiou) { maxiou = iou; best = t; }
        }
        const bool pos = maxiou > 0.5f;

        // class logits: max over C for obj loss (the mandatory 43MB stream)
        const float* cp = clsp + (size_t)(b * C_NUM) * A + a;
        float m = -INFINITY;
        #pragma unroll 8
        for (int c = 0; c < C_NUM; ++c) m = fmaxf(m, cp[(size_t)c * A]);
        objs = softplusf(m) - (pos ? m : 0.f);

        if (pos) {   // rare: softplus pass reloads from L1
            cnt = 1.f;
            float ssum = 0.f;
            #pragma unroll 4
            for (int c = 0; c < C_NUM; ++c) ssum += softplusf(cp[(size_t)c * A]);
            clss = ssum - cp[(size_t)s_tc[best] * A];
            // CIoU vs matched target
            float gx1 = s_x1[best], gy1 = s_y1[best], gx2 = s_x2[best], gy2 = s_y2[best];
            float gw = gx2 - gx1, gh = gy2 - gy1;
            float ix = fminf(px2, gx2) - fmaxf(px1, gx1);
            float iy = fminf(py2, gy2) - fmaxf(py1, gy1);
            float inter = fmaxf(ix, 0.f) * fmaxf(iy, 0.f);
            float uni = parea + gw * gh - inter + EPSF;
            float iou = inter / uni;
            float cw = fmaxf(px2, gx2) - fminf(px1, gx1);
            float ch = fmaxf(py2, gy2) - fminf(py1, gy1);
            float c2 = cw * cw + ch * ch + EPSF;
            float dx = 0.5f * ((px1 + px2) - (gx1 + gx2));
            float dy = 0.5f * ((py1 + py2) - (gy1 + gy2));
            float rho2 = dx * dx + dy * dy;
            float dv = atanf(gw / (gh + EPSF)) - atanf(pw / (ph + EPSF));
            float v = 0.40528473456935108577f * dv * dv;   // (4/pi^2) dv^2
            float alpha = v / (v - iou + 1.f + EPSF);
            boxs = 1.f - (iou - rho2 / c2 - alpha * v);
        }
    }

    // ---- block reduction: {npos, box, cls, obj} ----
    #pragma unroll
    for (int off = 32; off > 0; off >>= 1) {
        cnt  += __shfl_down(cnt,  off, 64);
        boxs += __shfl_down(boxs, off, 64);
        clss += __shfl_down(clss, off, 64);
        objs += __shfl_down(objs, off, 64);
    }
    if (lane == 0) {
        s_red[wave][0] = cnt;  s_red[wave][1] = boxs;
        s_red[wave][2] = clss; s_red[wave][3] = objs;
    }
    __syncthreads();
    if (tid == 0) {
        float rc = 0.f, rb = 0.f, rl = 0.f, ro = 0.f;
        #pragma unroll
        for (int w = 0; w < 4; ++w) {
            rc += s_red[w][0]; rb += s_red[w][1];
            rl += s_red[w][2]; ro += s_red[w][3];
        }
        atomicAdd(&acc[s * 4 + 0], rc);
        atomicAdd(&acc[s * 4 + 1], rb);
        atomicAdd(&acc[s * 4 + 2], rl);
        atomicAdd(&acc[s * 4 + 3], ro);
    }
}

__global__ __launch_bounds__(64)
void yolo_finalize(const float* __restrict__ acc, float* __restrict__ out) {
    if (threadIdx.x == 0) {
        const float inv_anchors[3] = { 1.f / (16.f * 6400.f), 1.f / (16.f * 1600.f), 1.f / (16.f * 400.f) };
        float total = 0.f;
        #pragma unroll
        for (int s = 0; s < 3; ++s) {
            float npos = fmaxf(acc[s * 4 + 0], 1.f);
            total += 7.5f * acc[s * 4 + 1] / npos
                   + 0.5f * acc[s * 4 + 2] / (npos * (float)C_NUM)
                   + acc[s * 4 + 3] * inv_anchors[s];
        }
        out[0] = total;
    }
}

extern "C" void kernel_launch(void* const* d_in, const int* in_sizes, int n_in,
                              void* d_out, int out_size, void* d_ws, size_t ws_size,
                              hipStream_t stream) {
    // Bind inputs by their (unique) flat sizes; the two 256-element int arrays
    // are t_batch then t_cls in dict order.
    const float *cls[3] = {nullptr, nullptr, nullptr};
    const float *reg[3] = {nullptr, nullptr, nullptr};
    const float *tboxes = nullptr;
    const int *t_batch = nullptr, *t_cls = nullptr;
    for (int i = 0; i < n_in; ++i) {
        switch (in_sizes[i]) {
            case 16 * 80 * 6400: cls[0] = (const float*)d_in[i]; break;
            case 16 * 80 * 1600: cls[1] = (const float*)d_in[i]; break;
            case 16 * 80 * 400:  cls[2] = (const float*)d_in[i]; break;
            case 16 * 4 * 6400:  reg[0] = (const float*)d_in[i]; break;
            case 16 * 4 * 1600:  reg[1] = (const float*)d_in[i]; break;
            case 16 * 4 * 400:   reg[2] = (const float*)d_in[i]; break;
            case 256 * 4:        tboxes = (const float*)d_in[i]; break;
            case 256:
                if (!t_batch) t_batch = (const int*)d_in[i];
                else          t_cls   = (const int*)d_in[i];
                break;
            default: break;
        }
    }
    float* acc = (float*)d_ws;          // 12 f32 accumulators: per scale {npos, box, cls, obj}
    float* out = (float*)d_out;

    hipLaunchKernelGGL(yolo_init, dim3(1), dim3(64), 0, stream, acc);
    hipLaunchKernelGGL(yolo_main, dim3(544), dim3(256), 0, stream,
                       cls[0], reg[0], cls[1], reg[1], cls[2], reg[2],
                       tboxes, t_batch, t_cls, acc);
    hipLaunchKernelGGL(yolo_finalize, dim3(1), dim3(64), 0, stream, acc, out);
}

// Round 2
// 139.479 us; speedup vs baseline: 1.1788x; 1.1788x over previous
//
#include <hip/hip_runtime.h>
#include <math.h>

#define C_NUM 80
#define B_NUM 16
#define T_NUM 256
#define EPSF  1e-7f

__device__ __forceinline__ float softplusf(float z) {
    // logaddexp(0, z) = max(z,0) + log1p(exp(-|z|)), numerically stable
    return fmaxf(z, 0.0f) + log1pf(expf(-fabsf(z)));
}

__global__ __launch_bounds__(64)
void yolo_init(float* __restrict__ acc) {
    if (threadIdx.x < 12) acc[threadIdx.x] = 0.0f;
}

// One block = 256-anchor tile of one (scale, image).
// bid < 400        : scale 0 (H=80, A=6400, 25 tiles x 16 images)
// 400 <= bid < 512 : scale 1 (H=40, A=1600,  7 tiles x 16 images)
// 512 <= bid < 544 : scale 2 (H=20, A=400,   2 tiles x 16 images)
//
// Class pass: wave w (0..3) covers classes [20w,20w+20); lane l covers tile
// anchors 4l..4l+3 via float4 loads -> 20 independent 1KB wave-loads (MLP).
__global__ __launch_bounds__(256)
void yolo_main(const float* __restrict__ cls0, const float* __restrict__ reg0,
               const float* __restrict__ cls1, const float* __restrict__ reg1,
               const float* __restrict__ cls2, const float* __restrict__ reg2,
               const float* __restrict__ tboxes, const int* __restrict__ t_batch,
               const int* __restrict__ t_cls, float* __restrict__ acc)
{
    __shared__ float s_x1[T_NUM], s_y1[T_NUM], s_x2[T_NUM], s_y2[T_NUM], s_ar[T_NUM];
    __shared__ int   s_tc[T_NUM];
    __shared__ int   s_list[T_NUM];
    __shared__ int   s_wcnt[4];
    __shared__ float4 s_pmax[4][64];   // [wave][lane] partial max, float4 = 4 anchors
    __shared__ float4 s_psum[4][64];   // [wave][lane] partial softplus sums (pos only)
    __shared__ int   s_pos[256];       // tile-anchor pos flag
    __shared__ int   s_btc[256];       // tile-anchor matched target class (if pos)
    __shared__ float s_red[4][4];

    const int tid = threadIdx.x;
    const int bid = blockIdx.x;

    int s, b, chunk, H; float stride;
    const float *clsp, *regp;
    if (bid < 400)      { s = 0; b = bid / 25;            chunk = bid % 25; clsp = cls0; regp = reg0; H = 80; stride =  8.f; }
    else if (bid < 512) { int r = bid - 400; s = 1; b = r / 7; chunk = r % 7; clsp = cls1; regp = reg1; H = 40; stride = 16.f; }
    else                { int r = bid - 512; s = 2; b = r / 2; chunk = r % 2; clsp = cls2; regp = reg2; H = 20; stride = 32.f; }
    const int A = H * H;

    // ---- stage all targets into LDS ----
    {
        float4 t4 = reinterpret_cast<const float4*>(tboxes)[tid];
        s_x1[tid] = t4.x; s_y1[tid] = t4.y; s_x2[tid] = t4.z; s_y2[tid] = t4.w;
        s_ar[tid] = (t4.z - t4.x) * (t4.w - t4.y);
        s_tc[tid] = t_cls[tid];
    }
    // ---- order-preserving compaction of targets with t_batch == b ----
    const int lane = tid & 63, wave = tid >> 6;
    int match = (t_batch[tid] == b) ? 1 : 0;
    unsigned long long mask = __ballot(match != 0);
    if (lane == 0) s_wcnt[wave] = __popcll(mask);
    __syncthreads();
    int base = 0;
    #pragma unroll
    for (int w = 0; w < 4; ++w) if (w < wave) base += s_wcnt[w];
    const int nT = s_wcnt[0] + s_wcnt[1] + s_wcnt[2] + s_wcnt[3];
    if (match) {
        int pfx = __popcll(mask & (((unsigned long long)1 << lane) - 1ull));
        s_list[base + pfx] = tid;
    }
    __syncthreads();

    // ---- step 2: per-anchor decode + IoU matching + CIoU (this thread owns tile anchor `tid`) ----
    const int a = chunk * 256 + tid;
    float cnt = 0.f, boxs = 0.f, clss = 0.f, objs = 0.f;
    bool pos = false;
    if (a < A) {
        const float* rp = regp + (b * 4) * A + a;
        float rx = rp[0], ry = rp[A], rw = rp[2 * A], rh = rp[3 * A];
        float gx = (float)(a % H), gy = (float)(a / H);
        float x = (1.f / (1.f + expf(-rx)) + gx) * stride;
        float y = (1.f / (1.f + expf(-ry)) + gy) * stride;
        float w = expf(rw) * stride;
        float h = expf(rh) * stride;
        float px1 = x - 0.5f * w, py1 = y - 0.5f * h;
        float px2 = x + 0.5f * w, py2 = y + 0.5f * h;
        float pw = px2 - px1, ph = py2 - py1;
        float parea = pw * ph;

        float maxiou = -1.f; int best = 0;
        for (int j = 0; j < nT; ++j) {
            int t = s_list[j];
            float ix = fminf(px2, s_x2[t]) - fmaxf(px1, s_x1[t]);
            float iy = fminf(py2, s_y2[t]) - fmaxf(py1, s_y1[t]);
            float inter = fmaxf(ix, 0.f) * fmaxf(iy, 0.f);
            float iou = inter / (parea + s_ar[t] - inter + EPSF);
            if (iou > maxiou) { maxiou = iou; best = t; }
        }
        pos = maxiou > 0.5f;
        s_pos[tid] = pos ? 1 : 0;
        s_btc[tid] = s_tc[best];

        if (pos) {
            cnt = 1.f;
            float gx1 = s_x1[best], gy1 = s_y1[best], gx2 = s_x2[best], gy2 = s_y2[best];
            float gw = gx2 - gx1, gh = gy2 - gy1;
            float ix = fminf(px2, gx2) - fmaxf(px1, gx1);
            float iy = fminf(py2, gy2) - fmaxf(py1, gy1);
            float inter = fmaxf(ix, 0.f) * fmaxf(iy, 0.f);
            float uni = parea + gw * gh - inter + EPSF;
            float iou = inter / uni;
            float cw = fmaxf(px2, gx2) - fminf(px1, gx1);
            float ch = fmaxf(py2, gy2) - fminf(py1, gy1);
            float c2 = cw * cw + ch * ch + EPSF;
            float dx = 0.5f * ((px1 + px2) - (gx1 + gx2));
            float dy = 0.5f * ((py1 + py2) - (gy1 + gy2));
            float rho2 = dx * dx + dy * dy;
            float dv = atanf(gw / (gh + EPSF)) - atanf(pw / (ph + EPSF));
            float v = 0.40528473456935108577f * dv * dv;   // (4/pi^2) dv^2
            float alpha = v / (v - iou + 1.f + EPSF);
            boxs = 1.f - (iou - rho2 / c2 - alpha * v);
        }
    } else {
        s_pos[tid] = 0;
        s_btc[tid] = 0;
    }
    __syncthreads();

    // ---- step 3: class pass. wave `wave` covers classes [20*wave, 20*wave+20),
    //      lane covers tile anchors 4*lane .. 4*lane+3 (float4). ----
    {
        const int ta0 = 4 * lane;
        const int a0  = chunk * 256 + ta0;
        const bool av = (a0 < A);             // A%4==0 -> all-or-nothing validity
        const float* cw = clsp + ((size_t)(b * C_NUM + 20 * wave)) * A + (av ? a0 : 0);
        const size_t cA = (size_t)A;

        float4 mx = make_float4(-INFINITY, -INFINITY, -INFINITY, -INFINITY);
        #pragma unroll
        for (int cl = 0; cl < 20; ++cl) {
            float4 z = *reinterpret_cast<const float4*>(cw + (size_t)cl * cA);
            mx.x = fmaxf(mx.x, z.x); mx.y = fmaxf(mx.y, z.y);
            mx.z = fmaxf(mx.z, z.z); mx.w = fmaxf(mx.w, z.w);
        }
        s_pmax[wave][lane] = mx;

        // cold path: softplus partial sums only for positive anchors (L1 reload)
        const int p0 = s_pos[ta0 + 0], p1 = s_pos[ta0 + 1];
        const int p2 = s_pos[ta0 + 2], p3 = s_pos[ta0 + 3];
        float4 sm = make_float4(0.f, 0.f, 0.f, 0.f);
        if (p0 | p1 | p2 | p3) {
            const int t0 = s_btc[ta0 + 0], t1 = s_btc[ta0 + 1];
            const int t2 = s_btc[ta0 + 2], t3 = s_btc[ta0 + 3];
            #pragma unroll 4
            for (int cl = 0; cl < 20; ++cl) {
                const int cg = 20 * wave + cl;
                float4 z = *reinterpret_cast<const float4*>(cw + (size_t)cl * cA);
                if (p0) { sm.x += softplusf(z.x); if (cg == t0) sm.x -= z.x; }
                if (p1) { sm.y += softplusf(z.y); if (cg == t1) sm.y -= z.y; }
                if (p2) { sm.z += softplusf(z.z); if (cg == t2) sm.z -= z.z; }
                if (p3) { sm.w += softplusf(z.w); if (cg == t3) sm.w -= z.w; }
            }
        }
        s_psum[wave][lane] = sm;
    }
    __syncthreads();

    // ---- step 4: owner thread combines the 4 per-wave partials for its anchor ----
    if (a < A) {
        const float* pm0 = reinterpret_cast<const float*>(s_pmax[0]);
        const float* pm1 = reinterpret_cast<const float*>(s_pmax[1]);
        const float* pm2 = reinterpret_cast<const float*>(s_pmax[2]);
        const float* pm3 = reinterpret_cast<const float*>(s_pmax[3]);
        float m = fmaxf(fmaxf(pm0[tid], pm1[tid]), fmaxf(pm2[tid], pm3[tid]));
        objs = softplusf(m) - (pos ? m : 0.f);
        if (pos) {
            clss = reinterpret_cast<const float*>(s_psum[0])[tid]
                 + reinterpret_cast<const float*>(s_psum[1])[tid]
                 + reinterpret_cast<const float*>(s_psum[2])[tid]
                 + reinterpret_cast<const float*>(s_psum[3])[tid];
        }
    }

    // ---- block reduction: {npos, box, cls, obj} ----
    #pragma unroll
    for (int off = 32; off > 0; off >>= 1) {
        cnt  += __shfl_down(cnt,  off, 64);
        boxs += __shfl_down(boxs, off, 64);
        clss += __shfl_down(clss, off, 64);
        objs += __shfl_down(objs, off, 64);
    }
    if (lane == 0) {
        s_red[wave][0] = cnt;  s_red[wave][1] = boxs;
        s_red[wave][2] = clss; s_red[wave][3] = objs;
    }
    __syncthreads();
    if (tid == 0) {
        float rc = 0.f, rb = 0.f, rl = 0.f, ro = 0.f;
        #pragma unroll
        for (int w = 0; w < 4; ++w) {
            rc += s_red[w][0]; rb += s_red[w][1];
            rl += s_red[w][2]; ro += s_red[w][3];
        }
        atomicAdd(&acc[s * 4 + 0], rc);
        atomicAdd(&acc[s * 4 + 1], rb);
        atomicAdd(&acc[s * 4 + 2], rl);
        atomicAdd(&acc[s * 4 + 3], ro);
    }
}

__global__ __launch_bounds__(64)
void yolo_finalize(const float* __restrict__ acc, float* __restrict__ out) {
    if (threadIdx.x == 0) {
        const float inv_anchors[3] = { 1.f / (16.f * 6400.f), 1.f / (16.f * 1600.f), 1.f / (16.f * 400.f) };
        float total = 0.f;
        #pragma unroll
        for (int s = 0; s < 3; ++s) {
            float npos = fmaxf(acc[s * 4 + 0], 1.f);
            total += 7.5f * acc[s * 4 + 1] / npos
                   + 0.5f * acc[s * 4 + 2] / (npos * (float)C_NUM)
                   + acc[s * 4 + 3] * inv_anchors[s];
        }
        out[0] = total;
    }
}

extern "C" void kernel_launch(void* const* d_in, const int* in_sizes, int n_in,
                              void* d_out, int out_size, void* d_ws, size_t ws_size,
                              hipStream_t stream) {
    const float *cls[3] = {nullptr, nullptr, nullptr};
    const float *reg[3] = {nullptr, nullptr, nullptr};
    const float *tboxes = nullptr;
    const int *t_batch = nullptr, *t_cls = nullptr;
    for (int i = 0; i < n_in; ++i) {
        switch (in_sizes[i]) {
            case 16 * 80 * 6400: cls[0] = (const float*)d_in[i]; break;
            case 16 * 80 * 1600: cls[1] = (const float*)d_in[i]; break;
            case 16 * 80 * 400:  cls[2] = (const float*)d_in[i]; break;
            case 16 * 4 * 6400:  reg[0] = (const float*)d_in[i]; break;
            case 16 * 4 * 1600:  reg[1] = (const float*)d_in[i]; break;
            case 16 * 4 * 400:   reg[2] = (const float*)d_in[i]; break;
            case 256 * 4:        tboxes = (const float*)d_in[i]; break;
            case 256:
                if (!t_batch) t_batch = (const int*)d_in[i];
                else          t_cls   = (const int*)d_in[i];
                break;
            default: break;
        }
    }
    float* acc = (float*)d_ws;   // 12 f32: per scale {npos, box, cls, obj}
    float* out = (float*)d_out;

    hipLaunchKernelGGL(yolo_init, dim3(1), dim3(64), 0, stream, acc);
    hipLaunchKernelGGL(yolo_main, dim3(544), dim3(256), 0, stream,
                       cls[0], reg[0], cls[1], reg[1], cls[2], reg[2],
                       tboxes, t_batch, t_cls, acc);
    hipLaunchKernelGGL(yolo_finalize, dim3(1), dim3(64), 0, stream, acc, out);
}